// Round 4
// baseline (623.850 us; speedup 1.0000x reference)
//
#include <hip/hip_runtime.h>

#define DD 64
#define ATT_SLOPE 0.2f
#define ACT_SLOPE 0.01f

// ---------------- CSR build ----------------
// edge_index: reference int64 [2,E], delivered by harness as int32
// ("integer -> const int*"), flat: src = ei[e], dst = ei[E+e].
// Self-loops (GATConv add_self_loops=True) appended as edges [E, E+N).

__global__ void zero_kernel(int* __restrict__ p, int n) {
    int i = blockIdx.x * blockDim.x + threadIdx.x;
    if (i < n) p[i] = 0;
}

__global__ void count_kernel(const int* __restrict__ ei, int E, int n_nodes,
                             int* __restrict__ counts) {
    int ET = E + n_nodes;
    int e = blockIdx.x * blockDim.x + threadIdx.x;
    if (e >= ET) return;
    int d = (e < E) ? ei[E + e] : (e - E);
    atomicAdd(&counts[d], 1);
}

// Single-block scan: counts -> row_ptr (size n+1); counts overwritten in-place
// with the exclusive prefix (reused as the scatter cursor).
__global__ void scan_kernel(int* __restrict__ counts, int* __restrict__ row_ptr, int n) {
    __shared__ int tile[1024];
    __shared__ int carry_s;
    int t = threadIdx.x;
    if (t == 0) { carry_s = 0; row_ptr[0] = 0; }
    __syncthreads();
    int niter = (n + 1023) / 1024;
    for (int it = 0; it < niter; ++it) {
        int i = it * 1024 + t;
        int v = (i < n) ? counts[i] : 0;
        tile[t] = v;
        __syncthreads();
        for (int off = 1; off < 1024; off <<= 1) {
            int add = (t >= off) ? tile[t - off] : 0;
            __syncthreads();
            tile[t] += add;
            __syncthreads();
        }
        int incl = tile[t] + carry_s;
        if (i < n) {
            row_ptr[i + 1] = incl;
            counts[i] = incl - v;     // exclusive prefix -> cursor (in place)
        }
        __syncthreads();
        if (t == 1023) carry_s = incl;
        __syncthreads();
    }
}

__global__ void scatter_kernel(const int* __restrict__ ei, int E, int n_nodes,
                               int* __restrict__ cursor, int* __restrict__ col_src) {
    int ET = E + n_nodes;
    int e = blockIdx.x * blockDim.x + threadIdx.x;
    if (e >= ET) return;
    int s, d;
    if (e < E) { s = ei[e]; d = ei[E + e]; }
    else       { s = e - E; d = s; }
    int pos = atomicAdd(&cursor[d], 1);
    col_src[pos] = s;
}

// ---------------- per-layer kernels ----------------

// h = in @ W.T  (h[n][j] = sum_k in[n][k] * W[j][k]), fused per-node
// alpha_src = h[n].a_src, alpha_dst = h[n].a_dst via wave shuffle reduction.
// block = 256 threads = 4 waves = 4 nodes; lane = output dim j.
__global__ void gemm_alpha_kernel(const float* __restrict__ in, const float* __restrict__ W,
                                  const float* __restrict__ a_src, const float* __restrict__ a_dst,
                                  float* __restrict__ h, float* __restrict__ as_out,
                                  float* __restrict__ ad_out, int n_nodes) {
    __shared__ float WT[64 * 65];   // WT[k*65+j] = W[j*64+k]; 65-stride: no bank conflicts
    __shared__ float xin[4 * 64];
    int t = threadIdx.x;
    int w = t >> 6, lane = t & 63;
    int node = blockIdx.x * 4 + w;

    #pragma unroll
    for (int i = 0; i < 16; ++i) {
        int idx = i * 256 + t;                 // coalesced read of W (4096 fp32)
        WT[(idx & 63) * 65 + (idx >> 6)] = W[idx];
    }
    int gi = blockIdx.x * 256 + t;
    xin[t] = (gi < n_nodes * 64) ? in[gi] : 0.f;
    __syncthreads();

    if (node >= n_nodes) return;

    float acc = 0.f;
    #pragma unroll
    for (int k = 0; k < 64; ++k)
        acc = fmaf(xin[w * 64 + k], WT[k * 65 + lane], acc);

    h[node * 64 + lane] = acc;

    float s1 = acc * a_src[lane];
    float s2 = acc * a_dst[lane];
    #pragma unroll
    for (int off = 32; off >= 1; off >>= 1) {
        s1 += __shfl_xor(s1, off, 64);
        s2 += __shfl_xor(s2, off, 64);
    }
    if (lane == 0) { as_out[node] = s1; ad_out[node] = s2; }
}

// One wave per dst node, lane = dim. Softmax over incoming edges (no max
// subtraction: logits are O(10), fp32 exp cannot overflow; self-loop
// guarantees denom > 0) + weighted sum of h[src].
__global__ void aggregate_kernel(const int* __restrict__ row_ptr, const int* __restrict__ col_src,
                                 const float* __restrict__ h, const float* __restrict__ as_arr,
                                 const float* __restrict__ ad_arr, const float* __restrict__ b,
                                 float* __restrict__ out, int n_nodes) {
    int t = threadIdx.x;
    int w = t >> 6, lane = t & 63;
    int node = blockIdx.x * 4 + w;
    if (node >= n_nodes) return;

    int beg = row_ptr[node], end = row_ptr[node + 1];
    float adn = ad_arr[node];
    float l = 0.f, acc = 0.f;
    for (int e = beg; e < end; ++e) {
        int s = col_src[e];
        float lg = as_arr[s] + adn;
        lg = (lg >= 0.f) ? lg : ATT_SLOPE * lg;
        float p = __expf(lg);
        l += p;
        acc = fmaf(p, h[s * 64 + lane], acc);
    }
    float o = acc / l + b[lane];
    o = (o >= 0.f) ? o : ACT_SLOPE * o;   // nn.LeakyReLU(0.01) after every GAT layer
    out[node * 64 + lane] = o;
}

// y[n] = h[n].Wout + bout  (OUT = 1), fp32 output.
__global__ void head_kernel(const float* __restrict__ h, const float* __restrict__ Wout,
                            const float* __restrict__ bout, float* __restrict__ y, int n_nodes) {
    int t = threadIdx.x;
    int w = t >> 6, lane = t & 63;
    int node = blockIdx.x * 4 + w;
    if (node >= n_nodes) return;
    float p = h[node * 64 + lane] * Wout[lane];
    #pragma unroll
    for (int off = 32; off >= 1; off >>= 1) p += __shfl_xor(p, off, 64);
    if (lane == 0) y[node] = p + bout[0];
}

// ---------------- launch ----------------

extern "C" void kernel_launch(void* const* d_in, const int* in_sizes, int n_in,
                              void* d_out, int out_size, void* d_ws, size_t ws_size,
                              hipStream_t stream) {
    const float* x     = (const float*)d_in[0];
    const float* W[3]  = {(const float*)d_in[1], (const float*)d_in[5], (const float*)d_in[9]};
    const float* as[3] = {(const float*)d_in[2], (const float*)d_in[6], (const float*)d_in[10]};
    const float* ad[3] = {(const float*)d_in[3], (const float*)d_in[7], (const float*)d_in[11]};
    const float* bv[3] = {(const float*)d_in[4], (const float*)d_in[8], (const float*)d_in[12]};
    const float* Wout  = (const float*)d_in[13];
    const float* bout  = (const float*)d_in[14];
    const int*   ei    = (const int*)d_in[15];   // int64 reference -> delivered int32

    const int N  = in_sizes[0] / DD;
    const int E  = in_sizes[15] / 2;
    const int ET = E + N;

    // workspace layout (~30.8 MB; validated by Round-3 run; 256 B aligned)
    char* ws = (char*)d_ws;
    size_t off = 0;
    auto alloc = [&](size_t bytes) {
        void* p = ws + off;
        off = (off + bytes + 255) & ~(size_t)255;
        return p;
    };
    int*   col_src = (int*)alloc((size_t)ET * 4);        // 3.4 MB
    int*   counts  = (int*)alloc((size_t)N * 4);         // 0.2 MB (doubles as cursor)
    int*   row_ptr = (int*)alloc((size_t)(N + 1) * 4);   // 0.2 MB
    float* as_arr  = (float*)alloc((size_t)N * 4);       // 0.2 MB
    float* ad_arr  = (float*)alloc((size_t)N * 4);       // 0.2 MB
    float* hbuf    = (float*)alloc((size_t)N * DD * 4);  // 12.8 MB
    float* obuf    = (float*)alloc((size_t)N * DD * 4);  // 12.8 MB
    (void)ws_size;

    int gridN  = (N + 255) / 256;
    int gridET = (ET + 255) / 256;
    int grid4  = (N + 3) / 4;

    // CSR build (dst identical across the 3 layers -> build once per call)
    zero_kernel<<<gridN, 256, 0, stream>>>(counts, N);
    count_kernel<<<gridET, 256, 0, stream>>>(ei, E, N, counts);
    scan_kernel<<<1, 1024, 0, stream>>>(counts, row_ptr, N);
    scatter_kernel<<<gridET, 256, 0, stream>>>(ei, E, N, counts, col_src);

    // 3 GAT layers: x/obuf -> (gemm) -> hbuf -> (aggregate) -> obuf
    const float* cur = x;
    for (int L = 0; L < 3; ++L) {
        gemm_alpha_kernel<<<grid4, 256, 0, stream>>>(cur, W[L], as[L], ad[L],
                                                     hbuf, as_arr, ad_arr, N);
        aggregate_kernel<<<grid4, 256, 0, stream>>>(row_ptr, col_src, hbuf, as_arr,
                                                    ad_arr, bv[L], obuf, N);
        cur = obuf;
    }

    // output head -> fp32
    head_kernel<<<grid4, 256, 0, stream>>>(obuf, Wout, bout, (float*)d_out, N);
}

// Round 5
// 547.546 us; speedup vs baseline: 1.1394x; 1.1394x over previous
//
#include <hip/hip_runtime.h>

#define DD 64
#define ATT_SLOPE 0.2f
#define ACT_SLOPE 0.01f
#define NPB 16   // nodes per block in gemm

// ---------------- CSR build ----------------
// edge_index delivered as int32, flat [2,E]: src = ei[e], dst = ei[E+e].
// Self-loops (GATConv add_self_loops=True) appended as edges [E, E+N).

__global__ void count_kernel(const int* __restrict__ ei, int E, int n_nodes,
                             int* __restrict__ counts) {
    int ET = E + n_nodes;
    int e = blockIdx.x * blockDim.x + threadIdx.x;
    if (e >= ET) return;
    int d = (e < E) ? ei[E + e] : (e - E);
    atomicAdd(&counts[d], 1);
}

// Single block, chunk-per-thread scan: thread t serially sums its ~49-elem
// chunk, 10-step block scan over the 1024 totals, then serial prefix
// write-back. counts -> exclusive prefix in place (cursor); row_ptr filled.
__global__ void scan_kernel(int* __restrict__ counts, int* __restrict__ row_ptr, int n) {
    __shared__ int tot[1024];
    int t = threadIdx.x;
    int C = (n + 1023) >> 10;
    int lo = t * C, hi = lo + C;
    if (hi > n) hi = n;
    int s = 0;
    for (int i = lo; i < hi; ++i) s += counts[i];
    tot[t] = s;
    __syncthreads();
    for (int off = 1; off < 1024; off <<= 1) {
        int add = (t >= off) ? tot[t - off] : 0;
        __syncthreads();
        tot[t] += add;
        __syncthreads();
    }
    int run = (t > 0) ? tot[t - 1] : 0;
    if (t == 0) row_ptr[0] = 0;
    for (int i = lo; i < hi; ++i) {
        int v = counts[i];
        counts[i] = run;          // exclusive prefix -> scatter cursor
        run += v;
        row_ptr[i + 1] = run;
    }
}

__global__ void scatter_kernel(const int* __restrict__ ei, int E, int n_nodes,
                               int* __restrict__ cursor, int* __restrict__ col_src) {
    int ET = E + n_nodes;
    int e = blockIdx.x * blockDim.x + threadIdx.x;
    if (e >= ET) return;
    int s, d;
    if (e < E) { s = ei[e]; d = ei[E + e]; }
    else       { s = e - E; d = s; }
    int pos = atomicAdd(&cursor[d], 1);
    col_src[pos] = s;
}

// ---------------- per-layer kernels ----------------

// h = in @ W.T, fused alpha_src/alpha_dst dots. 16 nodes per 256-thread
// block (W staging amortized 4x vs 4-node version); each wave computes 4
// nodes with 4 independent FMA chains; x read from LDS as float4.
__global__ __launch_bounds__(256) void gemm_alpha_kernel(
        const float* __restrict__ in, const float* __restrict__ W,
        const float* __restrict__ a_src, const float* __restrict__ a_dst,
        float* __restrict__ h, float* __restrict__ as_out,
        float* __restrict__ ad_out, int n_nodes) {
    __shared__ float WT[64 * 65];     // WT[k*65+j] = W[j*64+k]; 65-stride: 2-way max (free)
    __shared__ float xin[NPB * 64];   // 16 node rows
    int t = threadIdx.x;
    int w = t >> 6, lane = t & 63;
    int n64 = n_nodes * 64;

    #pragma unroll
    for (int i = 0; i < 16; ++i) {
        int idx = i * 256 + t;                 // coalesced read of W (4096 fp32)
        WT[(idx & 63) * 65 + (idx >> 6)] = W[idx];
    }
    int base = blockIdx.x * (NPB * 64);
    #pragma unroll
    for (int i = 0; i < (NPB * 64) / 256; ++i) {
        int gi = base + i * 256 + t;
        xin[i * 256 + t] = (gi < n64) ? in[gi] : 0.f;
    }
    __syncthreads();

    float asl = a_src[lane], adl = a_dst[lane];

    float acc0 = 0.f, acc1 = 0.f, acc2 = 0.f, acc3 = 0.f;
    const float4* x0 = (const float4*)&xin[(w * 4 + 0) * 64];
    const float4* x1 = (const float4*)&xin[(w * 4 + 1) * 64];
    const float4* x2 = (const float4*)&xin[(w * 4 + 2) * 64];
    const float4* x3 = (const float4*)&xin[(w * 4 + 3) * 64];
    #pragma unroll
    for (int kq = 0; kq < 16; ++kq) {
        float4 xa = x0[kq], xb = x1[kq], xc = x2[kq], xd = x3[kq];
        float w0 = WT[(4 * kq + 0) * 65 + lane];
        float w1 = WT[(4 * kq + 1) * 65 + lane];
        float w2 = WT[(4 * kq + 2) * 65 + lane];
        float w3 = WT[(4 * kq + 3) * 65 + lane];
        acc0 = fmaf(xa.x, w0, acc0); acc0 = fmaf(xa.y, w1, acc0);
        acc0 = fmaf(xa.z, w2, acc0); acc0 = fmaf(xa.w, w3, acc0);
        acc1 = fmaf(xb.x, w0, acc1); acc1 = fmaf(xb.y, w1, acc1);
        acc1 = fmaf(xb.z, w2, acc1); acc1 = fmaf(xb.w, w3, acc1);
        acc2 = fmaf(xc.x, w0, acc2); acc2 = fmaf(xc.y, w1, acc2);
        acc2 = fmaf(xc.z, w2, acc2); acc2 = fmaf(xc.w, w3, acc2);
        acc3 = fmaf(xd.x, w0, acc3); acc3 = fmaf(xd.y, w1, acc3);
        acc3 = fmaf(xd.z, w2, acc3); acc3 = fmaf(xd.w, w3, acc3);
    }

    float accs[4] = {acc0, acc1, acc2, acc3};
    #pragma unroll
    for (int r = 0; r < 4; ++r) {
        int node = blockIdx.x * NPB + w * 4 + r;
        if (node >= n_nodes) break;
        h[node * 64 + lane] = accs[r];
        float s1 = accs[r] * asl;
        float s2 = accs[r] * adl;
        #pragma unroll
        for (int off = 32; off >= 1; off >>= 1) {
            s1 += __shfl_xor(s1, off, 64);
            s2 += __shfl_xor(s2, off, 64);
        }
        if (lane == 0) { as_out[node] = s1; ad_out[node] = s2; }
    }
}

// One wave per dst node, lane = dim. Edge loop unrolled x4 with
// readfirstlane-scalarized indices: 4 independent h-row gathers in flight.
// No max-subtraction (logits O(10), fp32 exp safe; self-loop => denom > 0).
template <bool FUSE_HEAD>
__global__ __launch_bounds__(256) void aggregate_kernel(
        const int* __restrict__ row_ptr, const int* __restrict__ col_src,
        const float* __restrict__ h, const float* __restrict__ as_arr,
        const float* __restrict__ ad_arr, const float* __restrict__ b,
        float* __restrict__ out, const float* __restrict__ Wout,
        const float* __restrict__ bout, int n_nodes) {
    int t = threadIdx.x;
    int w = t >> 6, lane = t & 63;
    int node = blockIdx.x * 4 + w;
    if (node >= n_nodes) return;

    int beg = __builtin_amdgcn_readfirstlane(row_ptr[node]);
    int end = __builtin_amdgcn_readfirstlane(row_ptr[node + 1]);
    float adn = ad_arr[node];
    float l = 0.f, acc = 0.f;
    int e = beg;
    for (; e + 4 <= end; e += 4) {
        int s0 = __builtin_amdgcn_readfirstlane(col_src[e]);
        int s1 = __builtin_amdgcn_readfirstlane(col_src[e + 1]);
        int s2 = __builtin_amdgcn_readfirstlane(col_src[e + 2]);
        int s3 = __builtin_amdgcn_readfirstlane(col_src[e + 3]);
        float h0 = h[(size_t)s0 * 64 + lane];
        float h1 = h[(size_t)s1 * 64 + lane];
        float h2 = h[(size_t)s2 * 64 + lane];
        float h3 = h[(size_t)s3 * 64 + lane];
        float lg0 = as_arr[s0] + adn; lg0 = (lg0 >= 0.f) ? lg0 : ATT_SLOPE * lg0;
        float lg1 = as_arr[s1] + adn; lg1 = (lg1 >= 0.f) ? lg1 : ATT_SLOPE * lg1;
        float lg2 = as_arr[s2] + adn; lg2 = (lg2 >= 0.f) ? lg2 : ATT_SLOPE * lg2;
        float lg3 = as_arr[s3] + adn; lg3 = (lg3 >= 0.f) ? lg3 : ATT_SLOPE * lg3;
        float p0 = __expf(lg0), p1 = __expf(lg1), p2 = __expf(lg2), p3 = __expf(lg3);
        l += (p0 + p1) + (p2 + p3);
        acc = fmaf(p0, h0, acc);
        acc = fmaf(p1, h1, acc);
        acc = fmaf(p2, h2, acc);
        acc = fmaf(p3, h3, acc);
    }
    for (; e < end; ++e) {
        int s0 = __builtin_amdgcn_readfirstlane(col_src[e]);
        float lg = as_arr[s0] + adn;
        lg = (lg >= 0.f) ? lg : ATT_SLOPE * lg;
        float p = __expf(lg);
        l += p;
        acc = fmaf(p, h[(size_t)s0 * 64 + lane], acc);
    }
    float o = acc / l + b[lane];
    o = (o >= 0.f) ? o : ACT_SLOPE * o;   // nn.LeakyReLU(0.01)
    if (FUSE_HEAD) {
        float p = o * Wout[lane];
        #pragma unroll
        for (int off = 32; off >= 1; off >>= 1) p += __shfl_xor(p, off, 64);
        if (lane == 0) out[node] = p + bout[0];
    } else {
        out[node * 64 + lane] = o;
    }
}

// ---------------- launch ----------------

extern "C" void kernel_launch(void* const* d_in, const int* in_sizes, int n_in,
                              void* d_out, int out_size, void* d_ws, size_t ws_size,
                              hipStream_t stream) {
    const float* x     = (const float*)d_in[0];
    const float* W[3]  = {(const float*)d_in[1], (const float*)d_in[5], (const float*)d_in[9]};
    const float* as[3] = {(const float*)d_in[2], (const float*)d_in[6], (const float*)d_in[10]};
    const float* ad[3] = {(const float*)d_in[3], (const float*)d_in[7], (const float*)d_in[11]};
    const float* bv[3] = {(const float*)d_in[4], (const float*)d_in[8], (const float*)d_in[12]};
    const float* Wout  = (const float*)d_in[13];
    const float* bout  = (const float*)d_in[14];
    const int*   ei    = (const int*)d_in[15];   // int64 reference -> delivered int32

    const int N  = in_sizes[0] / DD;
    const int E  = in_sizes[15] / 2;
    const int ET = E + N;

    // workspace layout (~30.8 MB; 256 B aligned)
    char* ws = (char*)d_ws;
    size_t off = 0;
    auto alloc = [&](size_t bytes) {
        void* p = ws + off;
        off = (off + bytes + 255) & ~(size_t)255;
        return p;
    };
    int*   col_src = (int*)alloc((size_t)ET * 4);
    int*   counts  = (int*)alloc((size_t)N * 4);         // doubles as scatter cursor
    int*   row_ptr = (int*)alloc((size_t)(N + 1) * 4);
    float* as_arr  = (float*)alloc((size_t)N * 4);
    float* ad_arr  = (float*)alloc((size_t)N * 4);
    float* hbuf    = (float*)alloc((size_t)N * DD * 4);
    float* obuf    = (float*)alloc((size_t)N * DD * 4);
    (void)ws_size;

    int gridET = (ET + 255) / 256;
    int gridG  = (N + NPB - 1) / NPB;
    int grid4  = (N + 3) / 4;

    // CSR build (dst identical across the 3 layers -> build once per call)
    hipMemsetAsync(counts, 0, (size_t)N * 4, stream);
    count_kernel<<<gridET, 256, 0, stream>>>(ei, E, N, counts);
    scan_kernel<<<1, 1024, 0, stream>>>(counts, row_ptr, N);
    scatter_kernel<<<gridET, 256, 0, stream>>>(ei, E, N, counts, col_src);

    // 3 GAT layers; head fused into the last aggregate.
    const float* cur = x;
    for (int L = 0; L < 3; ++L) {
        gemm_alpha_kernel<<<gridG, 256, 0, stream>>>(cur, W[L], as[L], ad[L],
                                                     hbuf, as_arr, ad_arr, N);
        if (L < 2) {
            aggregate_kernel<false><<<grid4, 256, 0, stream>>>(
                row_ptr, col_src, hbuf, as_arr, ad_arr, bv[L], obuf,
                nullptr, nullptr, N);
        } else {
            aggregate_kernel<true><<<grid4, 256, 0, stream>>>(
                row_ptr, col_src, hbuf, as_arr, ad_arr, bv[L], (float*)d_out,
                Wout, bout, N);
        }
        cur = obuf;
    }
}

// Round 6
// 441.799 us; speedup vs baseline: 1.4121x; 1.2394x over previous
//
#include <hip/hip_runtime.h>

#define DD 64
#define ATT_SLOPE 0.2f
#define ACT_SLOPE 0.01f
#define NPB 16   // nodes per block in gemm

// ---------------- CSR build ----------------
// edge_index delivered as int32, flat [2,E]: src = ei[e], dst = ei[E+e].
// Self-loops (GATConv add_self_loops=True) appended as edges [E, E+N).

__global__ void count_kernel(const int* __restrict__ ei, int E, int n_nodes,
                             int* __restrict__ counts) {
    int ET = E + n_nodes;
    int e = blockIdx.x * blockDim.x + threadIdx.x;
    if (e >= ET) return;
    int d = (e < E) ? ei[E + e] : (e - E);
    atomicAdd(&counts[d], 1);
}

// Hierarchical scan, all coalesced, whole-GPU:
// k1: per-block (256 elems) local exclusive scan -> scan_tmp, block total -> blk
__global__ void scan_blocks_kernel(const int* __restrict__ counts,
                                   int* __restrict__ scan_tmp,
                                   int* __restrict__ blk, int n) {
    __shared__ int tile[256];
    int t = threadIdx.x;
    int i = blockIdx.x * 256 + t;
    int v = (i < n) ? counts[i] : 0;
    tile[t] = v;
    __syncthreads();
    #pragma unroll
    for (int off = 1; off < 256; off <<= 1) {
        int add = (t >= off) ? tile[t - off] : 0;
        __syncthreads();
        tile[t] += add;
        __syncthreads();
    }
    if (i < n) scan_tmp[i] = tile[t] - v;       // exclusive local
    if (t == 255) blk[blockIdx.x] = tile[255];  // block total
}

// k2: single block, exclusive scan of the <=256 block totals in place
__global__ void scan_carry_kernel(int* __restrict__ blk, int nb) {
    __shared__ int tile[256];
    int t = threadIdx.x;
    int v = (t < nb) ? blk[t] : 0;
    tile[t] = v;
    __syncthreads();
    #pragma unroll
    for (int off = 1; off < 256; off <<= 1) {
        int add = (t >= off) ? tile[t - off] : 0;
        __syncthreads();
        tile[t] += add;
        __syncthreads();
    }
    if (t < nb) blk[t] = tile[t] - v;           // exclusive
}

// k3: fix-up: counts[i] -> global exclusive prefix (scatter cursor),
//     row_ptr[i+1] = prefix + count, row_ptr[0] = 0.
__global__ void scan_final_kernel(int* __restrict__ counts,
                                  const int* __restrict__ scan_tmp,
                                  const int* __restrict__ blk,
                                  int* __restrict__ row_ptr, int n) {
    int i = blockIdx.x * 256 + threadIdx.x;
    if (i >= n) return;
    int excl = scan_tmp[i] + blk[blockIdx.x];
    int c = counts[i];
    counts[i] = excl;
    row_ptr[i + 1] = excl + c;
    if (i == 0) row_ptr[0] = 0;
}

__global__ void scatter_kernel(const int* __restrict__ ei, int E, int n_nodes,
                               int* __restrict__ cursor, int* __restrict__ col_src) {
    int ET = E + n_nodes;
    int e = blockIdx.x * blockDim.x + threadIdx.x;
    if (e >= ET) return;
    int s, d;
    if (e < E) { s = ei[e]; d = ei[E + e]; }
    else       { s = e - E; d = s; }
    int pos = atomicAdd(&cursor[d], 1);
    col_src[pos] = s;
}

// ---------------- per-layer kernels ----------------

// h = in @ W.T, fused alpha_src/alpha_dst dots. 16 nodes per 256-thread
// block; each wave computes 4 nodes with 4 independent FMA chains.
__global__ __launch_bounds__(256) void gemm_alpha_kernel(
        const float* __restrict__ in, const float* __restrict__ W,
        const float* __restrict__ a_src, const float* __restrict__ a_dst,
        float* __restrict__ h, float* __restrict__ as_out,
        float* __restrict__ ad_out, int n_nodes) {
    __shared__ float WT[64 * 65];     // WT[k*65+j] = W[j*64+k]; 2-way alias max (free)
    __shared__ float xin[NPB * 64];
    int t = threadIdx.x;
    int w = t >> 6, lane = t & 63;
    int n64 = n_nodes * 64;

    #pragma unroll
    for (int i = 0; i < 16; ++i) {
        int idx = i * 256 + t;
        WT[(idx & 63) * 65 + (idx >> 6)] = W[idx];
    }
    int base = blockIdx.x * (NPB * 64);
    #pragma unroll
    for (int i = 0; i < (NPB * 64) / 256; ++i) {
        int gi = base + i * 256 + t;
        xin[i * 256 + t] = (gi < n64) ? in[gi] : 0.f;
    }
    __syncthreads();

    float asl = a_src[lane], adl = a_dst[lane];

    float acc0 = 0.f, acc1 = 0.f, acc2 = 0.f, acc3 = 0.f;
    const float4* x0 = (const float4*)&xin[(w * 4 + 0) * 64];
    const float4* x1 = (const float4*)&xin[(w * 4 + 1) * 64];
    const float4* x2 = (const float4*)&xin[(w * 4 + 2) * 64];
    const float4* x3 = (const float4*)&xin[(w * 4 + 3) * 64];
    #pragma unroll
    for (int kq = 0; kq < 16; ++kq) {
        float4 xa = x0[kq], xb = x1[kq], xc = x2[kq], xd = x3[kq];
        float w0 = WT[(4 * kq + 0) * 65 + lane];
        float w1 = WT[(4 * kq + 1) * 65 + lane];
        float w2 = WT[(4 * kq + 2) * 65 + lane];
        float w3 = WT[(4 * kq + 3) * 65 + lane];
        acc0 = fmaf(xa.x, w0, acc0); acc0 = fmaf(xa.y, w1, acc0);
        acc0 = fmaf(xa.z, w2, acc0); acc0 = fmaf(xa.w, w3, acc0);
        acc1 = fmaf(xb.x, w0, acc1); acc1 = fmaf(xb.y, w1, acc1);
        acc1 = fmaf(xb.z, w2, acc1); acc1 = fmaf(xb.w, w3, acc1);
        acc2 = fmaf(xc.x, w0, acc2); acc2 = fmaf(xc.y, w1, acc2);
        acc2 = fmaf(xc.z, w2, acc2); acc2 = fmaf(xc.w, w3, acc2);
        acc3 = fmaf(xd.x, w0, acc3); acc3 = fmaf(xd.y, w1, acc3);
        acc3 = fmaf(xd.z, w2, acc3); acc3 = fmaf(xd.w, w3, acc3);
    }

    float accs[4] = {acc0, acc1, acc2, acc3};
    #pragma unroll
    for (int r = 0; r < 4; ++r) {
        int node = blockIdx.x * NPB + w * 4 + r;
        if (node >= n_nodes) break;
        h[node * 64 + lane] = accs[r];
        float s1 = accs[r] * asl;
        float s2 = accs[r] * adl;
        #pragma unroll
        for (int off = 32; off >= 1; off >>= 1) {
            s1 += __shfl_xor(s1, off, 64);
            s2 += __shfl_xor(s2, off, 64);
        }
        if (lane == 0) { as_out[node] = s1; ad_out[node] = s2; }
    }
}

// One wave per dst node. Lane l = (group g = l>>4, sub u = l&15); each lane
// holds float4 feature chunk u; the 4 groups process interleaved edge subsets
// (4 rows gathered per global_load_dwordx4 instruction -> 4 chains in flight).
// Cross-group combine via 2 shuffle-xor steps. No max-subtraction (logits
// O(10); self-loop => denom > 0).
template <bool FUSE_HEAD>
__global__ __launch_bounds__(256) void aggregate_kernel(
        const int* __restrict__ row_ptr, const int* __restrict__ col_src,
        const float* __restrict__ h, const float* __restrict__ as_arr,
        const float* __restrict__ ad_arr, const float* __restrict__ b,
        float* __restrict__ out, const float* __restrict__ Wout,
        const float* __restrict__ bout, int n_nodes) {
    int t = threadIdx.x;
    int w = t >> 6, lane = t & 63;
    int node = blockIdx.x * 4 + w;
    if (node >= n_nodes) return;
    int g = lane >> 4, u = lane & 15;

    int beg = __builtin_amdgcn_readfirstlane(row_ptr[node]);
    int end = __builtin_amdgcn_readfirstlane(row_ptr[node + 1]);
    float adn = ad_arr[node];

    float4 acc = {0.f, 0.f, 0.f, 0.f};
    float lsum = 0.f;
    int e = beg + g;
    int s = (e < end) ? col_src[e] : 0;          // prefetched index
    while (e < end) {
        int sc = s;
        int e2 = e + 4;
        if (e2 < end) s = col_src[e2];           // prefetch next index
        float lg = as_arr[sc] + adn;
        lg = (lg >= 0.f) ? lg : ATT_SLOPE * lg;
        float p = __expf(lg);
        const float4 hv = *(const float4*)(h + (size_t)sc * 64 + u * 4);
        lsum += p;
        acc.x = fmaf(p, hv.x, acc.x);
        acc.y = fmaf(p, hv.y, acc.y);
        acc.z = fmaf(p, hv.z, acc.z);
        acc.w = fmaf(p, hv.w, acc.w);
        e = e2;
    }
    // combine the 4 groups (lanes u, u+16, u+32, u+48)
    #pragma unroll
    for (int m = 16; m <= 32; m <<= 1) {
        acc.x += __shfl_xor(acc.x, m, 64);
        acc.y += __shfl_xor(acc.y, m, 64);
        acc.z += __shfl_xor(acc.z, m, 64);
        acc.w += __shfl_xor(acc.w, m, 64);
        lsum  += __shfl_xor(lsum, m, 64);
    }
    float inv = 1.f / lsum;
    const float4 bv4 = *(const float4*)(b + u * 4);
    float4 o;
    o.x = acc.x * inv + bv4.x; o.x = (o.x >= 0.f) ? o.x : ACT_SLOPE * o.x;
    o.y = acc.y * inv + bv4.y; o.y = (o.y >= 0.f) ? o.y : ACT_SLOPE * o.y;
    o.z = acc.z * inv + bv4.z; o.z = (o.z >= 0.f) ? o.z : ACT_SLOPE * o.z;
    o.w = acc.w * inv + bv4.w; o.w = (o.w >= 0.f) ? o.w : ACT_SLOPE * o.w;

    if (FUSE_HEAD) {
        const float4 wv = *(const float4*)(Wout + u * 4);
        float pd = o.x * wv.x + o.y * wv.y + o.z * wv.z + o.w * wv.w;
        #pragma unroll
        for (int m = 1; m <= 8; m <<= 1) pd += __shfl_xor(pd, m, 64);
        if (lane == 0) out[node] = pd + bout[0];
    } else {
        if (g == 0) *(float4*)(out + (size_t)node * 64 + u * 4) = o;
    }
}

// ---------------- launch ----------------

extern "C" void kernel_launch(void* const* d_in, const int* in_sizes, int n_in,
                              void* d_out, int out_size, void* d_ws, size_t ws_size,
                              hipStream_t stream) {
    const float* x     = (const float*)d_in[0];
    const float* W[3]  = {(const float*)d_in[1], (const float*)d_in[5], (const float*)d_in[9]};
    const float* as[3] = {(const float*)d_in[2], (const float*)d_in[6], (const float*)d_in[10]};
    const float* ad[3] = {(const float*)d_in[3], (const float*)d_in[7], (const float*)d_in[11]};
    const float* bv[3] = {(const float*)d_in[4], (const float*)d_in[8], (const float*)d_in[12]};
    const float* Wout  = (const float*)d_in[13];
    const float* bout  = (const float*)d_in[14];
    const int*   ei    = (const int*)d_in[15];   // int64 reference -> delivered int32

    const int N  = in_sizes[0] / DD;
    const int E  = in_sizes[15] / 2;
    const int ET = E + N;

    // workspace layout (~30.8 MB; 256 B aligned)
    char* ws = (char*)d_ws;
    size_t off = 0;
    auto alloc = [&](size_t bytes) {
        void* p = ws + off;
        off = (off + bytes + 255) & ~(size_t)255;
        return p;
    };
    int*   col_src = (int*)alloc((size_t)ET * 4);
    int*   counts  = (int*)alloc((size_t)N * 4);         // -> scatter cursor after scan
    int*   row_ptr = (int*)alloc((size_t)(N + 1) * 4);
    float* as_arr  = (float*)alloc((size_t)N * 4);
    float* ad_arr  = (float*)alloc((size_t)N * 4);
    float* hbuf    = (float*)alloc((size_t)N * DD * 4);
    float* obuf    = (float*)alloc((size_t)N * DD * 4);
    (void)ws_size;

    // scan temporaries alias obuf (first written by layer-0 aggregate, after scan)
    int* scan_tmp = (int*)obuf;          // N ints
    int* blk      = scan_tmp + N;        // <=256 ints

    int gridET = (ET + 255) / 256;
    int gridG  = (N + NPB - 1) / NPB;
    int grid4  = (N + 3) / 4;
    int nb     = (N + 255) / 256;        // 196 blocks (<= 256)

    // CSR build (dst identical across the 3 layers -> build once per call)
    hipMemsetAsync(counts, 0, (size_t)N * 4, stream);
    count_kernel<<<gridET, 256, 0, stream>>>(ei, E, N, counts);
    scan_blocks_kernel<<<nb, 256, 0, stream>>>(counts, scan_tmp, blk, N);
    scan_carry_kernel<<<1, 256, 0, stream>>>(blk, nb);
    scan_final_kernel<<<nb, 256, 0, stream>>>(counts, scan_tmp, blk, row_ptr, N);
    scatter_kernel<<<gridET, 256, 0, stream>>>(ei, E, N, counts, col_src);

    // 3 GAT layers; head fused into the last aggregate.
    const float* cur = x;
    for (int L = 0; L < 3; ++L) {
        gemm_alpha_kernel<<<gridG, 256, 0, stream>>>(cur, W[L], as[L], ad[L],
                                                     hbuf, as_arr, ad_arr, N);
        if (L < 2) {
            aggregate_kernel<false><<<grid4, 256, 0, stream>>>(
                row_ptr, col_src, hbuf, as_arr, ad_arr, bv[L], obuf,
                nullptr, nullptr, N);
        } else {
            aggregate_kernel<true><<<grid4, 256, 0, stream>>>(
                row_ptr, col_src, hbuf, as_arr, ad_arr, bv[L], (float*)d_out,
                Wout, bout, N);
        }
        cur = obuf;
    }
}